// Round 1
// baseline (3122.188 us; speedup 1.0000x reference)
//
#include <hip/hip_runtime.h>
#include <hip/hip_bf16.h>

#define D_MODEL 1024
#define NUM_HEADS 16
#define D_K 64
#define B_SZ 4
#define SEQ 2048

// ---------------------------------------------------------------------------
// GEMM: Y = A @ W + bias.  A [M,K] row-major, W [K,N] row-major, M=8192,
// N=K=1024.  64x64 tile, 256 threads, each thread 4x4 outputs, K-tile 16.
// mode 0: Y[row*N + col] (plain row-major)
// mode 1: split heads: Y[((b*H + h)*SEQ + s)*D_K + d], h=col/64, d=col%64
// ---------------------------------------------------------------------------
__global__ __launch_bounds__(256) void gemm64(
    const float* __restrict__ A, const float* __restrict__ W,
    const float* __restrict__ bias, float* __restrict__ Y, int mode)
{
    const int M = B_SZ * SEQ;
    const int N = D_MODEL;
    const int K = D_MODEL;

    __shared__ float As[16][65];   // [kk][row]
    __shared__ float Bs[16][65];   // [kk][col]

    const int t  = threadIdx.x;        // 0..255
    const int tx = t & 15;
    const int ty = t >> 4;
    const int row0 = blockIdx.y * 64;
    const int col0 = blockIdx.x * 64;

    // A-load mapping: each thread one float4; row = t/4, kk base = (t%4)*4
    const int arow = t >> 2;
    const int akk  = (t & 3) * 4;
    // B-load mapping: kk = t/16, col base = (t%16)*4
    const int bkk  = t >> 4;
    const int bcol = (t & 15) * 4;

    float acc[4][4] = {};

    for (int kt = 0; kt < K; kt += 16) {
        float4 av = *(const float4*)(A + (size_t)(row0 + arow) * K + kt + akk);
        As[akk + 0][arow] = av.x;
        As[akk + 1][arow] = av.y;
        As[akk + 2][arow] = av.z;
        As[akk + 3][arow] = av.w;

        float4 bv = *(const float4*)(W + (size_t)(kt + bkk) * N + col0 + bcol);
        Bs[bkk][bcol + 0] = bv.x;
        Bs[bkk][bcol + 1] = bv.y;
        Bs[bkk][bcol + 2] = bv.z;
        Bs[bkk][bcol + 3] = bv.w;

        __syncthreads();

        #pragma unroll
        for (int kk = 0; kk < 16; ++kk) {
            float a0 = As[kk][ty * 4 + 0];
            float a1 = As[kk][ty * 4 + 1];
            float a2 = As[kk][ty * 4 + 2];
            float a3 = As[kk][ty * 4 + 3];
            float b0 = Bs[kk][tx * 4 + 0];
            float b1 = Bs[kk][tx * 4 + 1];
            float b2 = Bs[kk][tx * 4 + 2];
            float b3 = Bs[kk][tx * 4 + 3];
            acc[0][0] = fmaf(a0, b0, acc[0][0]);
            acc[0][1] = fmaf(a0, b1, acc[0][1]);
            acc[0][2] = fmaf(a0, b2, acc[0][2]);
            acc[0][3] = fmaf(a0, b3, acc[0][3]);
            acc[1][0] = fmaf(a1, b0, acc[1][0]);
            acc[1][1] = fmaf(a1, b1, acc[1][1]);
            acc[1][2] = fmaf(a1, b2, acc[1][2]);
            acc[1][3] = fmaf(a1, b3, acc[1][3]);
            acc[2][0] = fmaf(a2, b0, acc[2][0]);
            acc[2][1] = fmaf(a2, b1, acc[2][1]);
            acc[2][2] = fmaf(a2, b2, acc[2][2]);
            acc[2][3] = fmaf(a2, b3, acc[2][3]);
            acc[3][0] = fmaf(a3, b0, acc[3][0]);
            acc[3][1] = fmaf(a3, b1, acc[3][1]);
            acc[3][2] = fmaf(a3, b2, acc[3][2]);
            acc[3][3] = fmaf(a3, b3, acc[3][3]);
        }
        __syncthreads();
    }

    #pragma unroll
    for (int i = 0; i < 4; ++i) {
        const int row = row0 + ty * 4 + i;
        #pragma unroll
        for (int j = 0; j < 4; ++j) {
            const int col = col0 + tx * 4 + j;
            const float val = acc[i][j] + bias[col];
            if (mode == 0) {
                Y[(size_t)row * N + col] = val;
            } else {
                const int bb = row / SEQ;
                const int s  = row % SEQ;
                const int h  = col / D_K;
                const int d  = col % D_K;
                Y[(((size_t)bb * NUM_HEADS + h) * SEQ + s) * D_K + d] = val;
            }
        }
    }
}

// ---------------------------------------------------------------------------
// Flash attention, fp32. One block = one (b, h, 64-row Q tile).
// Q/K/V layout: [B, H, S, D_K]. Output ctx layout: [B, S, H*D_K] row-major.
// ---------------------------------------------------------------------------
__global__ __launch_bounds__(256) void attn64(
    const float* __restrict__ Q, const float* __restrict__ Kg,
    const float* __restrict__ Vg, float* __restrict__ ctx)
{
    __shared__ float Qs[64][65];
    __shared__ float Ks[64][65];
    __shared__ float Vs[64][65];
    __shared__ float Ps[64][65];
    __shared__ float mrow[64], lrow[64], arow_s[64];

    const int t  = threadIdx.x;
    const int tx = t & 15;
    const int ty = t >> 4;
    const int qt = blockIdx.x;
    const int h  = blockIdx.y;
    const int b  = blockIdx.z;

    const size_t head_off = ((size_t)b * NUM_HEADS + h) * SEQ * D_K;
    const float* Qh = Q + head_off + (size_t)qt * 64 * D_K;

    // load Q tile (64x64 = 1024 float4s, 4 per thread)
    #pragma unroll
    for (int c = 0; c < 4; ++c) {
        const int idx = c * 256 + t;
        const int r   = idx >> 4;
        const int c4  = (idx & 15) * 4;
        float4 v = *(const float4*)(Qh + r * D_K + c4);
        Qs[r][c4 + 0] = v.x; Qs[r][c4 + 1] = v.y;
        Qs[r][c4 + 2] = v.z; Qs[r][c4 + 3] = v.w;
    }
    if (t < 64) { mrow[t] = -1e30f; lrow[t] = 0.0f; }

    float acc[4][4] = {};
    __syncthreads();

    for (int kt = 0; kt < SEQ / 64; ++kt) {
        const float* Kh = Kg + head_off + (size_t)kt * 64 * D_K;
        const float* Vh = Vg + head_off + (size_t)kt * 64 * D_K;
        #pragma unroll
        for (int c = 0; c < 4; ++c) {
            const int idx = c * 256 + t;
            const int r   = idx >> 4;
            const int c4  = (idx & 15) * 4;
            float4 kv = *(const float4*)(Kh + r * D_K + c4);
            Ks[r][c4 + 0] = kv.x; Ks[r][c4 + 1] = kv.y;
            Ks[r][c4 + 2] = kv.z; Ks[r][c4 + 3] = kv.w;
            float4 vv = *(const float4*)(Vh + r * D_K + c4);
            Vs[r][c4 + 0] = vv.x; Vs[r][c4 + 1] = vv.y;
            Vs[r][c4 + 2] = vv.z; Vs[r][c4 + 3] = vv.w;
        }
        __syncthreads();

        // scores: S = Q K^T / sqrt(64)
        float s[4][4] = {};
        #pragma unroll 8
        for (int d = 0; d < 64; ++d) {
            float q0 = Qs[ty * 4 + 0][d];
            float q1 = Qs[ty * 4 + 1][d];
            float q2 = Qs[ty * 4 + 2][d];
            float q3 = Qs[ty * 4 + 3][d];
            float k0 = Ks[tx * 4 + 0][d];
            float k1 = Ks[tx * 4 + 1][d];
            float k2 = Ks[tx * 4 + 2][d];
            float k3 = Ks[tx * 4 + 3][d];
            s[0][0] = fmaf(q0, k0, s[0][0]);
            s[0][1] = fmaf(q0, k1, s[0][1]);
            s[0][2] = fmaf(q0, k2, s[0][2]);
            s[0][3] = fmaf(q0, k3, s[0][3]);
            s[1][0] = fmaf(q1, k0, s[1][0]);
            s[1][1] = fmaf(q1, k1, s[1][1]);
            s[1][2] = fmaf(q1, k2, s[1][2]);
            s[1][3] = fmaf(q1, k3, s[1][3]);
            s[2][0] = fmaf(q2, k0, s[2][0]);
            s[2][1] = fmaf(q2, k1, s[2][1]);
            s[2][2] = fmaf(q2, k2, s[2][2]);
            s[2][3] = fmaf(q2, k3, s[2][3]);
            s[3][0] = fmaf(q3, k0, s[3][0]);
            s[3][1] = fmaf(q3, k1, s[3][1]);
            s[3][2] = fmaf(q3, k2, s[3][2]);
            s[3][3] = fmaf(q3, k3, s[3][3]);
        }
        #pragma unroll
        for (int i = 0; i < 4; ++i)
            #pragma unroll
            for (int j = 0; j < 4; ++j)
                Ps[ty * 4 + i][tx * 4 + j] = s[i][j] * 0.125f;
        __syncthreads();

        // online softmax bookkeeping, one thread per row
        if (t < 64) {
            const float m_old = mrow[t];
            float mx = m_old;
            #pragma unroll 8
            for (int c = 0; c < 64; ++c) mx = fmaxf(mx, Ps[t][c]);
            const float al = __expf(m_old - mx);
            float sum = 0.0f;
            #pragma unroll 8
            for (int c = 0; c < 64; ++c) {
                const float p = __expf(Ps[t][c] - mx);
                Ps[t][c] = p;
                sum += p;
            }
            mrow[t]   = mx;
            lrow[t]   = lrow[t] * al + sum;
            arow_s[t] = al;
        }
        __syncthreads();

        // O = O*alpha + P @ V
        #pragma unroll
        for (int i = 0; i < 4; ++i) {
            const float al = arow_s[ty * 4 + i];
            #pragma unroll
            for (int j = 0; j < 4; ++j) acc[i][j] *= al;
        }
        #pragma unroll 8
        for (int kc = 0; kc < 64; ++kc) {
            float p0 = Ps[ty * 4 + 0][kc];
            float p1 = Ps[ty * 4 + 1][kc];
            float p2 = Ps[ty * 4 + 2][kc];
            float p3 = Ps[ty * 4 + 3][kc];
            float v0 = Vs[kc][tx * 4 + 0];
            float v1 = Vs[kc][tx * 4 + 1];
            float v2 = Vs[kc][tx * 4 + 2];
            float v3 = Vs[kc][tx * 4 + 3];
            acc[0][0] = fmaf(p0, v0, acc[0][0]);
            acc[0][1] = fmaf(p0, v1, acc[0][1]);
            acc[0][2] = fmaf(p0, v2, acc[0][2]);
            acc[0][3] = fmaf(p0, v3, acc[0][3]);
            acc[1][0] = fmaf(p1, v0, acc[1][0]);
            acc[1][1] = fmaf(p1, v1, acc[1][1]);
            acc[1][2] = fmaf(p1, v2, acc[1][2]);
            acc[1][3] = fmaf(p1, v3, acc[1][3]);
            acc[2][0] = fmaf(p2, v0, acc[2][0]);
            acc[2][1] = fmaf(p2, v1, acc[2][1]);
            acc[2][2] = fmaf(p2, v2, acc[2][2]);
            acc[2][3] = fmaf(p2, v3, acc[2][3]);
            acc[3][0] = fmaf(p3, v0, acc[3][0]);
            acc[3][1] = fmaf(p3, v1, acc[3][1]);
            acc[3][2] = fmaf(p3, v2, acc[3][2]);
            acc[3][3] = fmaf(p3, v3, acc[3][3]);
        }
        __syncthreads();
    }

    // finalize: divide by l, write ctx in [B, S, H*D_K] layout
    #pragma unroll
    for (int i = 0; i < 4; ++i) {
        const int   qr   = qt * 64 + ty * 4 + i;
        const float linv = 1.0f / lrow[ty * 4 + i];
        #pragma unroll
        for (int j = 0; j < 4; ++j) {
            const int oc = tx * 4 + j;
            ctx[(((size_t)b * SEQ + qr) * NUM_HEADS + h) * D_K + oc] =
                acc[i][j] * linv;
        }
    }
}

// ---------------------------------------------------------------------------
extern "C" void kernel_launch(void* const* d_in, const int* in_sizes, int n_in,
                              void* d_out, int out_size, void* d_ws, size_t ws_size,
                              hipStream_t stream)
{
    const float* x  = (const float*)d_in[0];
    const float* Wq = (const float*)d_in[1];
    const float* bq = (const float*)d_in[2];
    const float* Wk = (const float*)d_in[3];
    const float* bk = (const float*)d_in[4];
    const float* Wv = (const float*)d_in[5];
    const float* bv = (const float*)d_in[6];
    const float* Wo = (const float*)d_in[7];
    const float* bo = (const float*)d_in[8];
    float* out = (float*)d_out;

    char* ws = (char*)d_ws;
    const size_t sz = (size_t)B_SZ * SEQ * D_MODEL * sizeof(float);  // 32 MB
    float* q   = (float*)(ws + 0 * sz);
    float* k   = (float*)(ws + 1 * sz);
    float* v   = (float*)(ws + 2 * sz);
    float* ctx = (float*)(ws + 3 * sz);

    dim3 gblk(256);
    dim3 ggrid(D_MODEL / 64, (B_SZ * SEQ) / 64);

    gemm64<<<ggrid, gblk, 0, stream>>>(x, Wq, bq, q, 1);
    gemm64<<<ggrid, gblk, 0, stream>>>(x, Wk, bk, k, 1);
    gemm64<<<ggrid, gblk, 0, stream>>>(x, Wv, bv, v, 1);

    dim3 agrid(SEQ / 64, NUM_HEADS, B_SZ);
    attn64<<<agrid, gblk, 0, stream>>>(q, k, v, ctx);

    gemm64<<<ggrid, gblk, 0, stream>>>(ctx, Wo, bo, out, 0);
}

// Round 2
// 289.997 us; speedup vs baseline: 10.7663x; 10.7663x over previous
//
#include <hip/hip_runtime.h>
#include <hip/hip_bf16.h>

#define D_MODEL 1024
#define NUM_HEADS 16
#define D_K 64
#define B_SZ 4
#define SEQ 2048

typedef short bf16x8 __attribute__((ext_vector_type(8)));
typedef float f32x4 __attribute__((ext_vector_type(4)));
typedef unsigned short u16;

union BF8 { bf16x8 v; uint4 q; };

__device__ __forceinline__ u16 f2bf(float f) {
    union { float f; unsigned u; } v; v.f = f;
    unsigned r = v.u + 0x7fffu + ((v.u >> 16) & 1u);
    return (u16)(r >> 16);
}

// ---------------------------------------------------------------------------
// cast x (fp32) -> bf16, vectorized: 8 floats -> 8 bf16 per thread-iter
// ---------------------------------------------------------------------------
__global__ __launch_bounds__(256) void cast_bf(
    const float* __restrict__ in, u16* __restrict__ out, int n8)
{
    int i = blockIdx.x * 256 + threadIdx.x;
    const int stride = gridDim.x * 256;
    for (; i < n8; i += stride) {
        float4 a = ((const float4*)in)[(size_t)i * 2];
        float4 b = ((const float4*)in)[(size_t)i * 2 + 1];
        BF8 o;
        o.v[0] = (short)f2bf(a.x); o.v[1] = (short)f2bf(a.y);
        o.v[2] = (short)f2bf(a.z); o.v[3] = (short)f2bf(a.w);
        o.v[4] = (short)f2bf(b.x); o.v[5] = (short)f2bf(b.y);
        o.v[6] = (short)f2bf(b.z); o.v[7] = (short)f2bf(b.w);
        ((uint4*)out)[i] = o.q;
    }
}

// ---------------------------------------------------------------------------
// W [1024 k][1024 n] fp32  ->  Wt [1024 n][1024 k] bf16   (4 matrices, z)
// ---------------------------------------------------------------------------
__global__ __launch_bounds__(256) void prep_w(
    const float* __restrict__ W0, const float* __restrict__ W1,
    const float* __restrict__ W2, const float* __restrict__ W3,
    u16* __restrict__ Wt)
{
    __shared__ float tile[64][65];
    const float* W = blockIdx.z == 0 ? W0 : blockIdx.z == 1 ? W1
                   : blockIdx.z == 2 ? W2 : W3;
    u16* out = Wt + (size_t)blockIdx.z * D_MODEL * D_MODEL;
    const int t  = threadIdx.x;
    const int k0 = blockIdx.y * 64;
    const int n0 = blockIdx.x * 64;
    #pragma unroll
    for (int it = 0; it < 4; ++it) {
        int idx = it * 256 + t;
        int r = idx >> 4;            // k-local
        int c = (idx & 15) * 4;      // n-local
        float4 v = *(const float4*)(W + (size_t)(k0 + r) * D_MODEL + n0 + c);
        tile[r][c + 0] = v.x; tile[r][c + 1] = v.y;
        tile[r][c + 2] = v.z; tile[r][c + 3] = v.w;
    }
    __syncthreads();
    #pragma unroll
    for (int it = 0; it < 2; ++it) {
        int idx = it * 256 + t;
        int r = idx >> 3;            // n-local
        int c = (idx & 7) * 8;       // k-local
        BF8 o;
        #pragma unroll
        for (int j = 0; j < 8; ++j) o.v[j] = (short)f2bf(tile[c + j][r]);
        *(uint4*)(out + (size_t)(n0 + r) * D_MODEL + k0 + c) = o.q;
    }
}

// ---------------------------------------------------------------------------
// GEMM: C[M=8192][1024] = A(bf16,[M][1024]) @ Bt^T (Bt bf16 [n][k]) + bias.
// 128x128 tile, BK=64, 4 waves, mfma_f32_16x16x32_bf16, padded LDS rows.
// mode 0: fp32 row-major out; mode 1: bf16 [B][H][S][64]; mode 2: bf16 V^T
// [B][H][64][S].
// ---------------------------------------------------------------------------
__global__ __launch_bounds__(256) void gemm_bf16(
    const u16* __restrict__ A, const u16* __restrict__ Bt,
    const float* __restrict__ bias, void* __restrict__ Y, int mode)
{
    __shared__ u16 As[128][72];
    __shared__ u16 Bs[128][72];
    const int t    = threadIdx.x;
    const int lane = t & 63;
    const int wid  = t >> 6;
    const int wm   = wid >> 1, wn = wid & 1;
    const int g    = lane >> 4;
    const int lr   = lane & 15;
    const int m0   = blockIdx.y * 128;
    const int n0   = blockIdx.x * 128;
    const int K    = D_MODEL;

    f32x4 acc[4][4];
    #pragma unroll
    for (int i = 0; i < 4; ++i)
        #pragma unroll
        for (int j = 0; j < 4; ++j)
            acc[i][j] = (f32x4){0.f, 0.f, 0.f, 0.f};

    for (int k0 = 0; k0 < K; k0 += 64) {
        #pragma unroll
        for (int it = 0; it < 4; ++it) {
            const int idx = it * 256 + t;
            const int r = idx >> 3;
            const int c = (idx & 7) * 8;
            *(uint4*)(&As[r][c]) = *(const uint4*)(A  + (size_t)(m0 + r) * K + k0 + c);
            *(uint4*)(&Bs[r][c]) = *(const uint4*)(Bt + (size_t)(n0 + r) * K + k0 + c);
        }
        __syncthreads();
        #pragma unroll
        for (int s = 0; s < 2; ++s) {
            bf16x8 af[4], bfr[4];
            #pragma unroll
            for (int mt = 0; mt < 4; ++mt)
                af[mt] = *(const bf16x8*)(&As[wm * 64 + mt * 16 + lr][g * 8 + s * 32]);
            #pragma unroll
            for (int nt = 0; nt < 4; ++nt)
                bfr[nt] = *(const bf16x8*)(&Bs[wn * 64 + nt * 16 + lr][g * 8 + s * 32]);
            #pragma unroll
            for (int mt = 0; mt < 4; ++mt)
                #pragma unroll
                for (int nt = 0; nt < 4; ++nt)
                    acc[mt][nt] = __builtin_amdgcn_mfma_f32_16x16x32_bf16(
                        af[mt], bfr[nt], acc[mt][nt], 0, 0, 0);
        }
        __syncthreads();
    }

    // bias values for this lane's 4 n-tiles
    float bv4[4];
    #pragma unroll
    for (int nt = 0; nt < 4; ++nt) bv4[nt] = bias[n0 + wn * 64 + nt * 16 + lr];

    #pragma unroll
    for (int mt = 0; mt < 4; ++mt) {
        #pragma unroll
        for (int nt = 0; nt < 4; ++nt) {
            #pragma unroll
            for (int r = 0; r < 4; ++r) {
                const int m = m0 + wm * 64 + mt * 16 + g * 4 + r;
                const int n = n0 + wn * 64 + nt * 16 + lr;
                const float val = acc[mt][nt][r] + bv4[nt];
                if (mode == 0) {
                    ((float*)Y)[(size_t)m * D_MODEL + n] = val;
                } else if (mode == 1) {
                    const int b = m >> 11, s2 = m & 2047;
                    const int h = n >> 6,  d  = n & 63;
                    ((u16*)Y)[(((size_t)(b * NUM_HEADS + h) * SEQ) + s2) * D_K + d] = f2bf(val);
                } else {
                    const int b = m >> 11, s2 = m & 2047;
                    const int h = n >> 6,  d  = n & 63;
                    ((u16*)Y)[(((size_t)(b * NUM_HEADS + h) * D_K + d) * SEQ) + s2] = f2bf(val);
                }
            }
        }
    }
}

// ---------------------------------------------------------------------------
// Flash attention, bf16 MFMA. Block = (64 q-rows, h, b), 4 waves x 16 q-rows.
// Swapped QK^T: S^T = mfma(K, Q) so each lane holds P values of its own q
// (q = lane&15), making the PV A-operand repack lane-local. V is consumed
// from V^T via two ds_read_b64 per fragment with a matching k-slot
// permutation sigma(g,j) = 4g + (j&3) + 16*(j>>2).
// ---------------------------------------------------------------------------
__global__ __launch_bounds__(256) void attn_mfma(
    const u16* __restrict__ Q, const u16* __restrict__ Kb,
    const u16* __restrict__ Vt, u16* __restrict__ ctx)
{
    __shared__ u16 Ks[64][72];
    __shared__ u16 Vs[64][68];
    const int t    = threadIdx.x;
    const int lane = t & 63;
    const int w    = t >> 6;
    const int g    = lane >> 4;
    const int lr   = lane & 15;
    const int qt   = blockIdx.x;
    const int h    = blockIdx.y;
    const int b    = blockIdx.z;
    const size_t hoff = ((size_t)b * NUM_HEADS + h) * SEQ * D_K;

    // Q fragments held in registers for the whole kernel
    const int q = qt * 64 + w * 16 + lr;
    bf16x8 qf[2];
    qf[0] = *(const bf16x8*)(Q + hoff + (size_t)q * D_K + g * 8);
    qf[1] = *(const bf16x8*)(Q + hoff + (size_t)q * D_K + g * 8 + 32);

    float mrun = -1e30f, lrun = 0.f;
    f32x4 acc_o[4];
    #pragma unroll
    for (int n = 0; n < 4; ++n) acc_o[n] = (f32x4){0.f, 0.f, 0.f, 0.f};

    for (int kt = 0; kt < SEQ / 64; ++kt) {
        const int kv0 = kt * 64;
        #pragma unroll
        for (int it = 0; it < 2; ++it) {
            const int idx = it * 256 + t;
            const int r = idx >> 3;
            const int c = (idx & 7) * 8;
            *(uint4*)(&Ks[r][c]) = *(const uint4*)(Kb + hoff + (size_t)(kv0 + r) * D_K + c);
            *(uint4*)(&Vs[r][c]) = *(const uint4*)(Vt + hoff + (size_t)r * SEQ + kv0 + c);
        }
        __syncthreads();

        // S^T tile: sc[mt] rows kv = 16mt + 4g + r, col q = lr
        f32x4 sc[4];
        #pragma unroll
        for (int mt = 0; mt < 4; ++mt) sc[mt] = (f32x4){0.f, 0.f, 0.f, 0.f};
        #pragma unroll
        for (int s = 0; s < 2; ++s)
            #pragma unroll
            for (int mt = 0; mt < 4; ++mt) {
                bf16x8 kf = *(const bf16x8*)(&Ks[mt * 16 + lr][g * 8 + s * 32]);
                sc[mt] = __builtin_amdgcn_mfma_f32_16x16x32_bf16(kf, qf[s], sc[mt], 0, 0, 0);
            }

        // online softmax (per lane: one q, 16 of 64 kv values)
        float p[4][4];
        float tmax = -1e30f;
        #pragma unroll
        for (int mt = 0; mt < 4; ++mt)
            #pragma unroll
            for (int r = 0; r < 4; ++r) {
                const float x = sc[mt][r] * 0.125f;
                p[mt][r] = x;
                tmax = fmaxf(tmax, x);
            }
        tmax = fmaxf(tmax, __shfl_xor(tmax, 16));
        tmax = fmaxf(tmax, __shfl_xor(tmax, 32));
        const float mnew  = fmaxf(mrun, tmax);
        const float alpha = __expf(mrun - mnew);
        float lsum = 0.f;
        #pragma unroll
        for (int mt = 0; mt < 4; ++mt)
            #pragma unroll
            for (int r = 0; r < 4; ++r) {
                const float e = __expf(p[mt][r] - mnew);
                p[mt][r] = e;
                lsum += e;
            }
        lsum += __shfl_xor(lsum, 16);
        lsum += __shfl_xor(lsum, 32);
        lrun = lrun * alpha + lsum;
        mrun = mnew;

        // rescale accumulator rows (acc_o row r belongs to q' = 4g + r)
        float ar[4];
        #pragma unroll
        for (int r = 0; r < 4; ++r) ar[r] = __shfl(alpha, g * 4 + r);
        #pragma unroll
        for (int n = 0; n < 4; ++n) {
            f32x4 v = acc_o[n];
            #pragma unroll
            for (int r = 0; r < 4; ++r) v[r] *= ar[r];
            acc_o[n] = v;
        }

        // P -> bf16 A fragments (lane-local): slot j <- p[2s + (j>>2)][j&3]
        bf16x8 pa[2];
        #pragma unroll
        for (int s = 0; s < 2; ++s) {
            #pragma unroll
            for (int j = 0; j < 4; ++j) pa[s][j]     = (short)f2bf(p[2 * s][j]);
            #pragma unroll
            for (int j = 0; j < 4; ++j) pa[s][4 + j] = (short)f2bf(p[2 * s + 1][j]);
        }

        // PV: acc_o[n] += pa[s] x Vt-frag(s, n)
        #pragma unroll
        for (int s = 0; s < 2; ++s)
            #pragma unroll
            for (int n = 0; n < 4; ++n) {
                const u16* base = &Vs[16 * n + lr][32 * s + 4 * g];
                union { bf16x8 v; uint2 u2[2]; } vf;
                vf.u2[0] = *(const uint2*)(base);
                vf.u2[1] = *(const uint2*)(base + 16);
                acc_o[n] = __builtin_amdgcn_mfma_f32_16x16x32_bf16(
                    pa[s], vf.v, acc_o[n], 0, 0, 0);
            }
        __syncthreads();
    }

    // finalize: divide by l (row q' = 4g + r), store ctx [B][S][H*64] bf16
    const float linv = 1.0f / lrun;
    float lr4[4];
    #pragma unroll
    for (int r = 0; r < 4; ++r) lr4[r] = __shfl(linv, g * 4 + r);
    #pragma unroll
    for (int n = 0; n < 4; ++n)
        #pragma unroll
        for (int r = 0; r < 4; ++r) {
            const int qrow = qt * 64 + w * 16 + 4 * g + r;
            ctx[((size_t)b * SEQ + qrow) * D_MODEL + h * D_K + 16 * n + lr] =
                f2bf(acc_o[n][r] * lr4[r]);
        }
}

// ---------------------------------------------------------------------------
extern "C" void kernel_launch(void* const* d_in, const int* in_sizes, int n_in,
                              void* d_out, int out_size, void* d_ws, size_t ws_size,
                              hipStream_t stream)
{
    const float* x  = (const float*)d_in[0];
    const float* Wq = (const float*)d_in[1];
    const float* bq = (const float*)d_in[2];
    const float* Wk = (const float*)d_in[3];
    const float* bk = (const float*)d_in[4];
    const float* Wv = (const float*)d_in[5];
    const float* bv = (const float*)d_in[6];
    const float* Wo = (const float*)d_in[7];
    const float* bo = (const float*)d_in[8];
    float* out = (float*)d_out;

    char* ws = (char*)d_ws;
    const size_t MB = 1024 * 1024;
    u16* xbf  = (u16*)(ws);                 // 16 MB
    u16* Wt   = (u16*)(ws + 16 * MB);       // 8 MB (4 x [1024][1024])
    u16* Qbf  = (u16*)(ws + 24 * MB);       // 16 MB [B][H][S][64]
    u16* Kbf  = (u16*)(ws + 40 * MB);       // 16 MB [B][H][S][64]
    u16* Vtw  = (u16*)(ws + 56 * MB);       // 16 MB [B][H][64][S]
    u16* ctxb = (u16*)(ws + 72 * MB);       // 16 MB [B][S][1024]

    cast_bf<<<2048, 256, 0, stream>>>(x, xbf, (B_SZ * SEQ * D_MODEL) / 8);
    prep_w<<<dim3(16, 16, 4), 256, 0, stream>>>(Wq, Wk, Wv, Wo, Wt);

    dim3 ggrid(D_MODEL / 128, (B_SZ * SEQ) / 128);
    gemm_bf16<<<ggrid, 256, 0, stream>>>(xbf, Wt + 0 * MB, bq, Qbf, 1);
    gemm_bf16<<<ggrid, 256, 0, stream>>>(xbf, Wt + 1 * MB, bk, Kbf, 1);
    gemm_bf16<<<ggrid, 256, 0, stream>>>(xbf, Wt + 2 * MB, bv, Vtw, 2);

    attn_mfma<<<dim3(SEQ / 64, NUM_HEADS, B_SZ), 256, 0, stream>>>(Qbf, Kbf, Vtw, ctxb);

    gemm_bf16<<<ggrid, 256, 0, stream>>>(ctxb, Wt + 3 * MB, bo, out, 0);
}